// Round 1
// baseline (122.454 us; speedup 1.0000x reference)
//
#include <hip/hip_runtime.h>
#include <hip/hip_bf16.h>

// WaveletLinear: y[b,o] = sum_i w[o,i] * (1 - s^2) * exp(-0.5 s^2)
//   s = (x[b,i] - t[o,i]) / (A_MIN + softplus(scale_raw[o,i]) + EPS)
// B=512, O=1024, I=512, fp32 in/out. Compute-bound on the fp32 VALU
// (no fp32 MFMA on CDNA4, and the nonlinearity kills matmul structure anyway).

#define WL_A_MIN 0.001f
#define WL_EPS   1e-8f

constexpr int WL_B = 512;
constexpr int WL_O = 1024;
constexpr int WL_I = 512;

constexpr int B_TILE = 64;   // b per block
constexpr int O_TILE = 16;   // o per block
constexpr int KC     = 64;   // i chunk

// LDS strides (floats), padded to keep 16B alignment and <=2-way bank conflicts
constexpr int P_STRIDE = KC * 4 + 4;  // 260 floats per o-row of float4 params
constexpr int X_STRIDE = KC + 4;      // 68 floats per b-row

__device__ __forceinline__ float fast_exp2(float a) {
#if defined(__has_builtin)
#if __has_builtin(__builtin_amdgcn_exp2f)
    return __builtin_amdgcn_exp2f(a);
#else
    return exp2f(a);
#endif
#else
    return exp2f(a);
#endif
}

// -0.5 * log2(e): exp(-0.5*s2) == exp2(kC * s2)
#define WL_KC (-0.72134752044448170368f)

// Kernel 1: precompute {nti, inv, w, 0} per (o,i) into workspace.
__global__ __launch_bounds__(256) void wl_precompute(
    const float* __restrict__ translation,
    const float* __restrict__ scale_raw,
    const float* __restrict__ weights,
    float4* __restrict__ ws4)
{
    int idx = blockIdx.x * 256 + threadIdx.x;
    if (idx >= WL_O * WL_I) return;
    float t  = translation[idx];
    float sr = scale_raw[idx];
    float w  = weights[idx];
    // softplus, sr in [-2,0] so exp(sr) <= 1: numerically fine
    float sp  = logf(1.0f + __expf(sr));
    float inv = 1.0f / (WL_A_MIN + sp + WL_EPS);
    ws4[idx] = make_float4(-t * inv, inv, w, 0.0f);
}

// Kernel 2: main wavelet-linear. Thread = 1 o x 4 b.
//   ox = tid & 15 (o within tile), bg = tid >> 4 (b-group of 4)
__global__ __launch_bounds__(256, 2) void wl_main(
    const float* __restrict__ x,
    const float4* __restrict__ p4,
    float* __restrict__ out)
{
    __shared__ float p_lds[O_TILE * P_STRIDE];  // 16*260*4  = 16640 B
    __shared__ float x_lds[B_TILE * X_STRIDE];  // 64*68*4   = 17408 B

    const int tid    = threadIdx.x;
    const int ox     = tid & 15;
    const int bg     = tid >> 4;          // 0..15
    const int o_base = blockIdx.y * O_TILE;
    const int b_base = blockIdx.x * B_TILE;

    float acc0 = 0.f, acc1 = 0.f, acc2 = 0.f, acc3 = 0.f;

    for (int kc = 0; kc < WL_I; kc += KC) {
        // --- stage params: 16 o x 64 i float4s; coalesced global, padded LDS ---
        #pragma unroll
        for (int k = 0; k < 4; ++k) {
            int lin = k * 256 + tid;      // 0..1023
            int o_l = lin >> 6;           // 0..15
            int i_l = lin & 63;           // 0..63
            float4 v = p4[(o_base + o_l) * WL_I + kc + i_l];
            *reinterpret_cast<float4*>(&p_lds[o_l * P_STRIDE + i_l * 4]) = v;
        }
        // --- stage x: 64 b x 64 i floats as float4 along i ---
        #pragma unroll
        for (int k = 0; k < 4; ++k) {
            int lin = k * 256 + tid;      // 0..1023
            int b_l = lin >> 4;           // 0..63
            int i4  = lin & 15;           // 0..15 -> i = i4*4
            float4 v = *reinterpret_cast<const float4*>(
                &x[(b_base + b_l) * WL_I + kc + i4 * 4]);
            *reinterpret_cast<float4*>(&x_lds[b_l * X_STRIDE + i4 * 4]) = v;
        }
        __syncthreads();

        const float* xr = &x_lds[(bg * 4) * X_STRIDE];
        const float* pr = &p_lds[ox * P_STRIDE];

        #pragma unroll 8
        for (int i = 0; i < KC; ++i) {
            float4 p = *reinterpret_cast<const float4*>(&pr[i * 4]);
            const float nti = p.x, inv = p.y, w = p.z;
            const float x0 = xr[i];
            const float x1 = xr[X_STRIDE + i];
            const float x2 = xr[2 * X_STRIDE + i];
            const float x3 = xr[3 * X_STRIDE + i];

            {
                float s  = fmaf(x0, inv, nti);
                float s2 = s * s;
                float e  = fast_exp2(s2 * (float)WL_KC);
                float pt = fmaf(-s2, e, e);          // (1 - s2) * e
                acc0 = fmaf(w, pt, acc0);
            }
            {
                float s  = fmaf(x1, inv, nti);
                float s2 = s * s;
                float e  = fast_exp2(s2 * (float)WL_KC);
                float pt = fmaf(-s2, e, e);
                acc1 = fmaf(w, pt, acc1);
            }
            {
                float s  = fmaf(x2, inv, nti);
                float s2 = s * s;
                float e  = fast_exp2(s2 * (float)WL_KC);
                float pt = fmaf(-s2, e, e);
                acc2 = fmaf(w, pt, acc2);
            }
            {
                float s  = fmaf(x3, inv, nti);
                float s2 = s * s;
                float e  = fast_exp2(s2 * (float)WL_KC);
                float pt = fmaf(-s2, e, e);
                acc3 = fmaf(w, pt, acc3);
            }
        }
        __syncthreads();
    }

    const int o  = o_base + ox;
    const int b0 = b_base + bg * 4;
    out[(b0 + 0) * WL_O + o] = acc0;
    out[(b0 + 1) * WL_O + o] = acc1;
    out[(b0 + 2) * WL_O + o] = acc2;
    out[(b0 + 3) * WL_O + o] = acc3;
}

extern "C" void kernel_launch(void* const* d_in, const int* in_sizes, int n_in,
                              void* d_out, int out_size, void* d_ws, size_t ws_size,
                              hipStream_t stream) {
    const float* x           = (const float*)d_in[0];
    const float* translation = (const float*)d_in[1];
    const float* scale_raw   = (const float*)d_in[2];
    const float* weights     = (const float*)d_in[3];
    float*       out         = (float*)d_out;
    float4*      ws4         = (float4*)d_ws;   // needs O*I*16 = 8 MB

    // Kernel 1: param precompute (softplus fused away from the hot loop)
    wl_precompute<<<dim3((WL_O * WL_I + 255) / 256), dim3(256), 0, stream>>>(
        translation, scale_raw, weights, ws4);

    // Kernel 2: main compute. 8 x 64 = 512 blocks, 2 blocks/CU.
    wl_main<<<dim3(WL_B / B_TILE, WL_O / O_TILE), dim3(256), 0, stream>>>(
        x, ws4, out);
}

// Round 2
// 113.392 us; speedup vs baseline: 1.0799x; 1.0799x over previous
//
#include <hip/hip_runtime.h>
#include <hip/hip_bf16.h>

// WaveletLinear fused single-kernel:
//   y[b,o] = sum_i w[o,i] * (1 - s^2) * exp(-0.5 s^2),
//   s = (x[b,i] - t[o,i]) / (A_MIN + softplus(sr[o,i]) + EPS)
// Rework: u = K*s^2 with K = 0.5*log2(e); e = exp2(-u);
//   contribution = w*e - (w/K)*(u*e)
// Per-(o,i) params {nti, inv, w, w2} computed in-kernel per chunk (softplus
// via hw exp2/log2/rcp — ~3% of inner-loop cycles, kills the 2nd kernel).
// Inner math in float2 packed ops -> v_pk_fma_f32 / v_pk_mul_f32.

#define WL_A_MIN 0.001f
#define WL_EPS   1e-8f

constexpr int WL_B = 512;
constexpr int WL_O = 1024;
constexpr int WL_I = 512;

constexpr int O_TILE = 16;
constexpr int B_TILE = 32;
constexpr int KC     = 64;

constexpr int PS = KC * 4 + 4;      // param row stride (floats), 16B-aligned rows
constexpr int XS = B_TILE + 4;      // transposed-x row stride (floats), mult of 4

// K = 0.5*log2(e); sqrt(K); 1/K
#define WL_K    0.72134752044448170368f
#define WL_SQK  0.84932180553704583800f
#define WL_IK   1.38629436111989061883f
#define WL_L2E  1.44269504088896340736f
#define WL_LN2  0.69314718055994530942f

typedef float v2f __attribute__((ext_vector_type(2)));

__device__ __forceinline__ float fast_exp2(float a) {
#if __has_builtin(__builtin_amdgcn_exp2f)
    return __builtin_amdgcn_exp2f(a);
#else
    return exp2f(a);
#endif
}
__device__ __forceinline__ float fast_log2(float a) {
#if __has_builtin(__builtin_amdgcn_logf)
    return __builtin_amdgcn_logf(a);
#else
    return __log2f(a);
#endif
}
__device__ __forceinline__ float fast_rcp(float a) {
#if __has_builtin(__builtin_amdgcn_rcpf)
    return __builtin_amdgcn_rcpf(a);
#else
    return 1.0f / a;
#endif
}

// grid = (O/O_TILE=64, B/B_TILE=16). blockIdx.x = o-tile so that all 16
// b-tiles of one o-tile land on the same XCD (linear%8 == bx%8) -> params
// for an o-tile are fetched into one XCD's L2 once.
__global__ __launch_bounds__(256, 4) void wl_fused(
    const float* __restrict__ x,
    const float* __restrict__ translation,
    const float* __restrict__ scale_raw,
    const float* __restrict__ weights,
    float* __restrict__ out)
{
    __shared__ float p_lds[O_TILE * PS];   // 16*260*4 = 16640 B
    __shared__ float x_lds[KC * XS];       // 64*36*4  =  9216 B

    const int tid    = threadIdx.x;
    const int ox     = tid & 15;           // o within tile
    const int bg     = tid >> 4;           // 0..15, b-pair index
    const int o_base = blockIdx.x * O_TILE;
    const int b_base = blockIdx.y * B_TILE;

    v2f acc = {0.0f, 0.0f};

    for (int kc = 0; kc < WL_I; kc += KC) {
        // ---- stage params: 16 o x 64 i, 4 per thread, coalesced global ----
        #pragma unroll
        for (int k = 0; k < 4; ++k) {
            int lin = k * 256 + tid;               // 0..1023
            int o_l = lin >> 6;                    // 0..15
            int i_l = lin & 63;                    // 0..63
            int gi  = (o_base + o_l) * WL_I + kc + i_l;
            float t  = translation[gi];
            float sr = scale_raw[gi];
            float w  = weights[gi];
            // softplus via hw exp2/log2: log(1+exp(sr)) = log2(1+exp2(sr*log2e))*ln2
            float ex  = fast_exp2(sr * WL_L2E);
            float sp  = fast_log2(1.0f + ex) * WL_LN2;
            float inv = fast_rcp(WL_A_MIN + sp + WL_EPS);
            float inv_s = inv * WL_SQK;            // inv * sqrt(K)
            float4 pv = make_float4(-t * inv_s, inv_s, w, w * WL_IK);
            *reinterpret_cast<float4*>(&p_lds[o_l * PS + i_l * 4]) = pv;
        }
        // ---- stage x transposed: x_lds[i][b], conflict-free scalar writes ----
        {
            int b_r = tid & 31;                    // one b-row per thread
            int ig  = tid >> 5;                    // 0..7 -> i base ig*8
            const float4* xr = reinterpret_cast<const float4*>(
                &x[(b_base + b_r) * WL_I + kc + ig * 8]);
            float4 v0 = xr[0];
            float4 v1 = xr[1];
            int base = (ig * 8) * XS + b_r;
            x_lds[base + 0 * XS] = v0.x;
            x_lds[base + 1 * XS] = v0.y;
            x_lds[base + 2 * XS] = v0.z;
            x_lds[base + 3 * XS] = v0.w;
            x_lds[base + 4 * XS] = v1.x;
            x_lds[base + 5 * XS] = v1.y;
            x_lds[base + 6 * XS] = v1.z;
            x_lds[base + 7 * XS] = v1.w;
        }
        __syncthreads();

        const float* pr = &p_lds[ox * PS];

        #pragma unroll 8
        for (int i = 0; i < KC; ++i) {
            float4 p = *reinterpret_cast<const float4*>(&pr[i * 4]);
            v2f x2 = *reinterpret_cast<const v2f*>(&x_lds[i * XS + bg * 2]);
            v2f inv2 = {p.y, p.y};
            v2f nti2 = {p.x, p.x};
            v2f s  = __builtin_elementwise_fma(x2, inv2, nti2);  // v_pk_fma_f32
            v2f u  = s * s;                                      // v_pk_mul_f32
            v2f e  = {fast_exp2(-u.x), fast_exp2(-u.y)};         // 2x v_exp_f32
            v2f w2  = {p.z, p.z};
            acc = __builtin_elementwise_fma(w2, e, acc);         // += w*e
            v2f ue = u * e;                                      // v_pk_mul_f32
            v2f nw2 = {-p.w, -p.w};
            acc = __builtin_elementwise_fma(nw2, ue, acc);       // -= (w/K)*u*e
        }
        __syncthreads();
    }

    const int o = o_base + ox;
    const int b = b_base + bg * 2;
    out[(b + 0) * WL_O + o] = acc.x;
    out[(b + 1) * WL_O + o] = acc.y;
}

extern "C" void kernel_launch(void* const* d_in, const int* in_sizes, int n_in,
                              void* d_out, int out_size, void* d_ws, size_t ws_size,
                              hipStream_t stream) {
    const float* x           = (const float*)d_in[0];
    const float* translation = (const float*)d_in[1];
    const float* scale_raw   = (const float*)d_in[2];
    const float* weights     = (const float*)d_in[3];
    float*       out         = (float*)d_out;

    wl_fused<<<dim3(WL_O / O_TILE, WL_B / B_TILE), dim3(256), 0, stream>>>(
        x, translation, scale_raw, weights, out);
}